// Round 10
// baseline (1043.987 us; speedup 1.0000x reference)
//
#include <hip/hip_runtime.h>
#include <hip/hip_cooperative_groups.h>
#include <cstdint>
#include <cstddef>

namespace cg = cooperative_groups;

#define NN 20000

typedef __bf16 bf16_t;
typedef __bf16 bf16x8 __attribute__((ext_vector_type(8)));
typedef float f32x4 __attribute__((ext_vector_type(4)));

#define AS1 __attribute__((address_space(1)))
#define AS3 __attribute__((address_space(3)))

__device__ __forceinline__ float lrelu(float x) { return x >= 0.f ? x : 0.2f * x; }
__device__ __forceinline__ float bflo(uint32_t u) { return __uint_as_float(u << 16); }
__device__ __forceinline__ float bfhi(uint32_t u) { return __uint_as_float(u & 0xffff0000u); }

__device__ __forceinline__ uint32_t pack2bf(float a, float b) {
  bf16_t x = (bf16_t)a, y = (bf16_t)b;
  uint16_t ux = __builtin_bit_cast(uint16_t, x);
  uint16_t uy = __builtin_bit_cast(uint16_t, y);
  return (uint32_t)ux | ((uint32_t)uy << 16);
}

// ---------------- CSR scan ----------------

__global__ __launch_bounds__(1024) void scan_kernel(const int* __restrict__ cnt,
                                                    int* __restrict__ row_ptr,
                                                    int* __restrict__ cursor, int n) {
  __shared__ int wsum[16];
  const int t = threadIdx.x;
  const int lane = t & 63, w = t >> 6;
  int carry = 0;
  for (int base = 0; base < n; base += 1024) {
    int i = base + t;
    int v = (i < n) ? cnt[i] : 0;
    int x = v;
#pragma unroll
    for (int d = 1; d < 64; d <<= 1) {
      int y = __shfl_up(x, d);
      if (lane >= d) x += y;
    }
    if (lane == 63) wsum[w] = x;
    __syncthreads();
    if (t < 16) {
      int s = wsum[t];
#pragma unroll
      for (int d = 1; d < 16; d <<= 1) {
        int y = __shfl_up(s, d);
        if (t >= d) s += y;
      }
      wsum[t] = s;
    }
    __syncthreads();
    int blocksum = wsum[15];
    int wprefix = (w == 0) ? 0 : wsum[w - 1];
    int excl = carry + wprefix + (x - v);
    if (i < n) { row_ptr[i] = excl; cursor[i] = excl; }
    carry += blocksum;
    __syncthreads();
  }
  if (t == 0) row_ptr[n] = carry;
}

// ---------------- prep mega-kernel (weights / projections / hist) ----------------

struct WDesc { const float* W; bf16_t* Bt; int K; int Cw; int H; float scale; int b0; };
struct WPack { WDesc d[4]; };

struct Prep1Args {
  WPack wp;
  const float *W1, *as1, *ad1, *W2, *as2, *ad2, *W3, *as3, *ad3;
  float *P1, *P2, *P3;
  const float *W3m, *L1w, *b3v, *l1b;
  bf16_t* M3t; float* bm;
  const int* ei; int E, N, EB;
  int* cnt;
};

__global__ __launch_bounds__(256) void prep1(Prep1Args a) {
  __shared__ float tile[32][33];
  const int b = blockIdx.x;
  const int t = threadIdx.x;

  if (b < 204) {
    int i = 3;
#pragma unroll
    for (int k = 2; k >= 0; --k)
      if (b < a.wp.d[k + 1].b0) i = k;
    const WDesc de = a.wp.d[i];
    const int bi = b - de.b0;
    const int ktiles = de.K / 32;
    const int kt = bi % ktiles, rt = bi / ktiles;
    const int gc = rt * 32;
    const int h = gc / de.Cw, c0 = gc % de.Cw;
    const int tx = t & 31, ty = t >> 5;
#pragma unroll
    for (int r = 0; r < 32; r += 8)
      tile[ty + r][tx] = de.W[(size_t)(kt * 32 + ty + r) * (de.H * de.Cw) + h * de.Cw + c0 + tx];
    __syncthreads();
#pragma unroll
    for (int r = 0; r < 32; r += 8)
      de.Bt[(size_t)(c0 + ty + r) * (de.H * de.K) + h * de.K + kt * 32 + tx] =
          (bf16_t)(de.scale * tile[tx][ty + r]);
  } else if (b < 716) {
    const int kk = b - 204;
    const float *W, *asrc, *adst;
    float* P;
    int K, H, k;
    if (kk < 256)      { W = a.W1; asrc = a.as1; adst = a.ad1; P = a.P1; K = 256; H = 4; k = kk; }
    else if (kk < 384) { W = a.W2; asrc = a.as2; adst = a.ad2; P = a.P2; K = 128; H = 4; k = kk - 256; }
    else               { W = a.W3; asrc = a.as3; adst = a.ad3; P = a.P3; K = 128; H = 1; k = kk - 384; }
    for (int j = 0; j < 2 * H; ++j) {
      const int h = (j < H) ? j : j - H;
      const float* av = (j < H) ? asrc : adst;
      float pv = 0.f;
      if (t < 128) pv = W[(size_t)k * (H * 128) + h * 128 + t] * av[h * 128 + t];
#pragma unroll
      for (int d = 1; d < 64; d <<= 1) pv += __shfl_xor(pv, d);
      if (t == 0 || t == 64) tile[0][t >> 6] = pv;
      __syncthreads();
      if (t == 0) P[j * K + k] = tile[0][0] + tile[0][1];
      __syncthreads();
    }
  } else if (b < 780) {
    const int idx = (b - 716) * 256 + t;
    const int k = idx >> 7, c = idx & 127;
    float s = 0.f;
    for (int m = 0; m < 128; ++m) s += a.W3m[k * 128 + m] * a.L1w[m * 128 + c];
    a.M3t[c * 128 + k] = (bf16_t)s;
    if (k == 0) {
      float tt = a.l1b[c];
      for (int m = 0; m < 128; ++m) tt += a.b3v[m] * a.L1w[m * 128 + c];
      a.bm[c] = tt;
    }
  } else {
    const int i = (b - 780) * 256 + t;
    if (i < a.E + a.N) {
      int dst = (i < a.E) ? a.ei[a.E + i] : (i - a.E);
      atomicAdd(&a.cnt[dst], 1);
    }
  }
}

// ---------------- mega-kernel args ----------------

struct MegaArgs {
  // scatter + cast
  const int* ei; int E, N, EB;
  int* cursor; int* col;
  const float* x; const float* P1;
  bf16_t* xb; float* asadA;
  // pipeline buffers
  bf16_t *aggb, *f1b, *f2b;
  float *asadB, *asadC;
  const int* rp;
  // weights
  const bf16_t *Ws1t, *Ws2t, *M3t, *l2t, *l3t;
  const float *P2, *P3;
  const float *b1, *bn1g, *bn1b, *bn1m, *bn1v;
  const float *b2, *bn2g, *bn2b, *bn2m, *bn2v;
  const float *bm, *l2b, *l3b;
  float* out;
};

// ---------------- device phase functions ----------------

__device__ void scatter_cast_dev(const MegaArgs& a, int b) {
  const int t = threadIdx.x;
  if (b < a.EB) {
    const int i = b * 256 + t;
    if (i < a.E + a.N) {
      int src, dst;
      if (i < a.E) { src = a.ei[i]; dst = a.ei[a.E + i]; }
      else         { src = i - a.E; dst = src; }
      int slot = atomicAdd(&a.cursor[dst], 1);
      a.col[slot] = src;
    }
  } else {
    const int wv = t >> 6, lane = t & 63;
    const int n = (b - a.EB) * 4 + wv;
    const float4 v = *(const float4*)&a.x[(size_t)n * 256 + lane * 4];
    uint2 ov;
    ov.x = pack2bf(v.x, v.y);
    ov.y = pack2bf(v.z, v.w);
    *(uint2*)&a.xb[(size_t)n * 256 + lane * 4] = ov;
    float s[8];
#pragma unroll
    for (int j = 0; j < 8; ++j) {
      const float4 pj = *(const float4*)&a.P1[j * 256 + lane * 4];
      s[j] = v.x * pj.x + v.y * pj.y + v.z * pj.z + v.w * pj.w;
    }
#pragma unroll
    for (int j = 0; j < 8; ++j)
#pragma unroll
      for (int d = 1; d < 64; d <<= 1) s[j] += __shfl_xor(s[j], d);
    if (lane == 0) {
#pragma unroll
      for (int j = 0; j < 8; ++j) a.asadA[(size_t)n * 8 + j] = s[j];
    }
  }
}

// gemm: C = act(A @ Bt^T + bias), TM=128 TN=64 BK=64, grid-stride over tiles.
// act: 1=relu, 2=sigmoid, 3=BN+relu. Cb (bf16) or Cf (float).
__device__ void gemm_dev(char* smem, const bf16_t* A, const bf16_t* Bt,
                         const float* bias, const float* bng, const float* bnb,
                         const float* bnm, const float* bnv, int act,
                         bf16_t* Cb, float* Cf, int M, int N, int K) {
  bf16_t* As = (bf16_t*)smem;            // 128*64 bf16 = 16 KB
  bf16_t* Bs = (bf16_t*)(smem + 16384);  // 64*64 bf16 = 8 KB
  const int t = threadIdx.x;
  const int wave = t >> 6, lane = t & 63;
  const int ln15 = lane & 15, quad = lane >> 4;
  const int gx = (M + 127) >> 7;
  const int ntile = gx * (N >> 6);
  const size_t strideAB = (size_t)K * 2;

  for (int tile = blockIdx.x; tile < ntile; tile += gridDim.x) {
    const int bm = (tile % gx) * 128;
    const int bn = (tile / gx) * 64;
    const int wm = wave * 32;
    const int rowLimA = M - 1 - bm;

    f32x4 acc[2][4];
#pragma unroll
    for (int mi = 0; mi < 2; ++mi)
#pragma unroll
      for (int ni = 0; ni < 4; ++ni) acc[mi][ni] = (f32x4){0.f, 0.f, 0.f, 0.f};

    const char* gA = (const char*)A + (size_t)bm * strideAB;
    const char* gB = (const char*)Bt + (size_t)bn * strideAB;

    for (int k0 = 0; k0 < K; k0 += 64) {
#pragma unroll
      for (int r = 0; r < 4; ++r) {
        int base = (wave * 4 + r) * 1024;
        int flat = base + lane * 16;
        int row = flat >> 7;
        int grow = row < rowLimA ? row : rowLimA;
        const char* gp = gA + (size_t)grow * strideAB + (size_t)(k0 * 2) + (flat & 127);
        __builtin_amdgcn_global_load_lds((const AS1 void*)gp,
                                         (AS3 void*)((char*)As + base), 16, 0, 0);
      }
#pragma unroll
      for (int r = 0; r < 2; ++r) {
        int base = (wave * 2 + r) * 1024;
        int flat = base + lane * 16;
        int row = flat >> 7;
        const char* gp = gB + (size_t)row * strideAB + (size_t)(k0 * 2) + (flat & 127);
        __builtin_amdgcn_global_load_lds((const AS1 void*)gp,
                                         (AS3 void*)((char*)Bs + base), 16, 0, 0);
      }
      __syncthreads();
#pragma unroll
      for (int kk = 0; kk < 64; kk += 32) {
        bf16x8 af[2], bfr[4];
#pragma unroll
        for (int mi = 0; mi < 2; ++mi)
          af[mi] = *(const bf16x8*)&As[(wm + mi * 16 + ln15) * 64 + kk + quad * 8];
#pragma unroll
        for (int ni = 0; ni < 4; ++ni)
          bfr[ni] = *(const bf16x8*)&Bs[(ni * 16 + ln15) * 64 + kk + quad * 8];
#pragma unroll
        for (int mi = 0; mi < 2; ++mi)
#pragma unroll
          for (int ni = 0; ni < 4; ++ni)
            acc[mi][ni] = __builtin_amdgcn_mfma_f32_16x16x32_bf16(af[mi], bfr[ni], acc[mi][ni], 0, 0, 0);
      }
      __syncthreads();
    }

#pragma unroll
    for (int mi = 0; mi < 2; ++mi) {
      int r0 = bm + wm + mi * 16 + quad * 4;
#pragma unroll
      for (int ni = 0; ni < 4; ++ni) {
        int c = bn + ni * 16 + ln15;
        float bv = bias[c];
        float sc = 1.f, sh = 0.f;
        if (act == 3) {
          sc = bng[c] * rsqrtf(bnv[c] + 1e-5f);
          sh = bnb[c] - bnm[c] * sc;
        }
#pragma unroll
        for (int reg = 0; reg < 4; ++reg) {
          int r = r0 + reg;
          if (r < M) {
            float v = acc[mi][ni][reg] + bv;
            if (act == 1) v = fmaxf(v, 0.f);
            else if (act == 2) v = 1.f / (1.f + __expf(-v));
            else v = fmaxf(v * sc + sh, 0.f);
            if (Cb) Cb[(size_t)r * N + c] = (bf16_t)v;
            else    Cf[(size_t)r * N + c] = v;
          }
        }
      }
    }
  }
}

// alpha logits: asad[n, j] = f[n,:] . P[j,:]
template <int K, int H>
__device__ void alpha_dev(const bf16_t* f, const float* P, float* asad, int N) {
  constexpr int J = 2 * H;
  constexpr int KC = K / 64;
  const int wv = threadIdx.x >> 6, lane = threadIdx.x & 63;
  for (int grp = blockIdx.x; grp < N / 4; grp += gridDim.x) {
    const int n = grp * 4 + wv;
    float v[KC];
    if (KC == 4) {
      uint2 pv = *(const uint2*)&f[(size_t)n * K + lane * 4];
      v[0] = bflo(pv.x); v[1] = bfhi(pv.x); v[2] = bflo(pv.y); v[3] = bfhi(pv.y);
    } else {
      uint32_t pv = *(const uint32_t*)&f[(size_t)n * K + lane * 2];
      v[0] = bflo(pv); v[1] = bfhi(pv);
    }
    float s[J];
#pragma unroll
    for (int j = 0; j < J; ++j) {
      float acc = 0.f;
#pragma unroll
      for (int q = 0; q < KC; ++q) acc += v[q] * P[j * K + lane * KC + q];
      s[j] = acc;
    }
#pragma unroll
    for (int j = 0; j < J; ++j)
#pragma unroll
      for (int d = 1; d < 64; d <<= 1) s[j] += __shfl_xor(s[j], d);
    if (lane == 0) {
#pragma unroll
      for (int j = 0; j < J; ++j) asad[(size_t)n * J + j] = s[j];
    }
  }
}

// input-space GAT aggregation, H=4, wave per node (4 waves/block), grid-stride
template <int K>
__device__ void gather4_dev(char* smem, const bf16_t* f, const float* asad,
                            const int* rp, const int* cs, bf16_t* agg, int N) {
  constexpr int KC = K / 64;
  int* sb = (int*)smem;                   // [4][64]
  float4* wl = (float4*)(smem + 1024);    // [4][64]
  const int wv = threadIdx.x >> 6, lane = threadIdx.x & 63;
  const char* fb = (const char*)f;
  const size_t loff = (size_t)lane * (KC * 2);

  for (int grp = blockIdx.x; grp < N / 4; grp += gridDim.x) {
    const int n = grp * 4 + wv;
    const int r0 = rp[n], r1 = rp[n + 1];
    const int deg = r1 - r0;
    const float4 adv = *(const float4*)&asad[(size_t)n * 8 + 4];

    float acc[4][KC];
#pragma unroll
    for (int j = 0; j < 4; ++j)
#pragma unroll
      for (int q = 0; q < KC; ++q) acc[j][q] = 0.f;

    auto edge_fma = [&](const char* gp, float4 w4) {
      if (KC == 4) {
        uint2 b = *(const uint2*)gp;
        float v0 = bflo(b.x), v1 = bfhi(b.x), v2 = bflo(b.y), v3 = bfhi(b.y);
        acc[0][0] += w4.x * v0; acc[0][1] += w4.x * v1; acc[0][2] += w4.x * v2; acc[0][3] += w4.x * v3;
        acc[1][0] += w4.y * v0; acc[1][1] += w4.y * v1; acc[1][2] += w4.y * v2; acc[1][3] += w4.y * v3;
        acc[2][0] += w4.z * v0; acc[2][1] += w4.z * v1; acc[2][2] += w4.z * v2; acc[2][3] += w4.z * v3;
        acc[3][0] += w4.w * v0; acc[3][1] += w4.w * v1; acc[3][2] += w4.w * v2; acc[3][3] += w4.w * v3;
      } else {
        uint32_t b = *(const uint32_t*)gp;
        float v0 = bflo(b), v1 = bfhi(b);
        acc[0][0] += w4.x * v0; acc[0][1] += w4.x * v1;
        acc[1][0] += w4.y * v0; acc[1][1] += w4.y * v1;
        acc[2][0] += w4.z * v0; acc[2][1] += w4.z * v1;
        acc[3][0] += w4.w * v0; acc[3][1] += w4.w * v1;
      }
    };

    if (deg <= 64) {
      const bool valid = lane < deg;
      int s = 0;
      float e0 = -1e30f, e1 = -1e30f, e2 = -1e30f, e3 = -1e30f;
      if (valid) {
        s = cs[r0 + lane];
        const float4 av = *(const float4*)&asad[(size_t)s * 8];
        e0 = lrelu(av.x + adv.x); e1 = lrelu(av.y + adv.y);
        e2 = lrelu(av.z + adv.z); e3 = lrelu(av.w + adv.w);
      }
      float m0 = e0, m1 = e1, m2 = e2, m3 = e3;
#pragma unroll
      for (int d = 1; d < 64; d <<= 1) {
        m0 = fmaxf(m0, __shfl_xor(m0, d)); m1 = fmaxf(m1, __shfl_xor(m1, d));
        m2 = fmaxf(m2, __shfl_xor(m2, d)); m3 = fmaxf(m3, __shfl_xor(m3, d));
      }
      float x0 = valid ? __expf(e0 - m0) : 0.f;
      float x1 = valid ? __expf(e1 - m1) : 0.f;
      float x2 = valid ? __expf(e2 - m2) : 0.f;
      float x3 = valid ? __expf(e3 - m3) : 0.f;
      float d0 = x0, d1 = x1, d2 = x2, d3 = x3;
#pragma unroll
      for (int d = 1; d < 64; d <<= 1) {
        d0 += __shfl_xor(d0, d); d1 += __shfl_xor(d1, d);
        d2 += __shfl_xor(d2, d); d3 += __shfl_xor(d3, d);
      }
      if (valid) {
        sb[wv * 64 + lane] = s * (K * 2);
        wl[wv * 64 + lane] = make_float4(x0 / (d0 + 1e-16f), x1 / (d1 + 1e-16f),
                                         x2 / (d2 + 1e-16f), x3 / (d3 + 1e-16f));
      }
      __builtin_amdgcn_wave_barrier();

      int g = 0;
      for (; g + 8 <= deg; g += 8) {
        const char* p[8];
        float4 w[8];
#pragma unroll
        for (int k = 0; k < 8; ++k) {
          p[k] = fb + (size_t)sb[wv * 64 + g + k] + loff;
          w[k] = wl[wv * 64 + g + k];
        }
        if (KC == 4) {
          uint2 b[8];
#pragma unroll
          for (int k = 0; k < 8; ++k) b[k] = *(const uint2*)p[k];
#pragma unroll
          for (int k = 0; k < 8; ++k) {
            float v0 = bflo(b[k].x), v1 = bfhi(b[k].x), v2 = bflo(b[k].y), v3 = bfhi(b[k].y);
            acc[0][0] += w[k].x * v0; acc[0][1] += w[k].x * v1; acc[0][2] += w[k].x * v2; acc[0][3] += w[k].x * v3;
            acc[1][0] += w[k].y * v0; acc[1][1] += w[k].y * v1; acc[1][2] += w[k].y * v2; acc[1][3] += w[k].y * v3;
            acc[2][0] += w[k].z * v0; acc[2][1] += w[k].z * v1; acc[2][2] += w[k].z * v2; acc[2][3] += w[k].z * v3;
            acc[3][0] += w[k].w * v0; acc[3][1] += w[k].w * v1; acc[3][2] += w[k].w * v2; acc[3][3] += w[k].w * v3;
          }
        } else {
          uint32_t b[8];
#pragma unroll
          for (int k = 0; k < 8; ++k) b[k] = *(const uint32_t*)p[k];
#pragma unroll
          for (int k = 0; k < 8; ++k) {
            float v0 = bflo(b[k]), v1 = bfhi(b[k]);
            acc[0][0] += w[k].x * v0; acc[0][1] += w[k].x * v1;
            acc[1][0] += w[k].y * v0; acc[1][1] += w[k].y * v1;
            acc[2][0] += w[k].z * v0; acc[2][1] += w[k].z * v1;
            acc[3][0] += w[k].w * v0; acc[3][1] += w[k].w * v1;
          }
        }
      }
      for (; g < deg; ++g)
        edge_fma(fb + (size_t)sb[wv * 64 + g] + loff, wl[wv * 64 + g]);
    } else {
      // deg > 64 fallback
      float m0 = -1e30f, m1 = -1e30f, m2 = -1e30f, m3 = -1e30f;
      for (int i = r0 + lane; i < r1; i += 64) {
        const float4 av = *(const float4*)&asad[(size_t)cs[i] * 8];
        m0 = fmaxf(m0, lrelu(av.x + adv.x)); m1 = fmaxf(m1, lrelu(av.y + adv.y));
        m2 = fmaxf(m2, lrelu(av.z + adv.z)); m3 = fmaxf(m3, lrelu(av.w + adv.w));
      }
#pragma unroll
      for (int d = 1; d < 64; d <<= 1) {
        m0 = fmaxf(m0, __shfl_xor(m0, d)); m1 = fmaxf(m1, __shfl_xor(m1, d));
        m2 = fmaxf(m2, __shfl_xor(m2, d)); m3 = fmaxf(m3, __shfl_xor(m3, d));
      }
      float d0 = 0.f, d1 = 0.f, d2 = 0.f, d3 = 0.f;
      for (int i = r0 + lane; i < r1; i += 64) {
        const float4 av = *(const float4*)&asad[(size_t)cs[i] * 8];
        d0 += __expf(lrelu(av.x + adv.x) - m0); d1 += __expf(lrelu(av.y + adv.y) - m1);
        d2 += __expf(lrelu(av.z + adv.z) - m2); d3 += __expf(lrelu(av.w + adv.w) - m3);
      }
#pragma unroll
      for (int d = 1; d < 64; d <<= 1) {
        d0 += __shfl_xor(d0, d); d1 += __shfl_xor(d1, d);
        d2 += __shfl_xor(d2, d); d3 += __shfl_xor(d3, d);
      }
      const float i0 = 1.f / (d0 + 1e-16f), i1 = 1.f / (d1 + 1e-16f);
      const float i2 = 1.f / (d2 + 1e-16f), i3 = 1.f / (d3 + 1e-16f);
      for (int base = r0; base < r1; base += 64) {
        const int ne = min(64, r1 - base);
        if (lane < ne) {
          const int s = cs[base + lane];
          const float4 av = *(const float4*)&asad[(size_t)s * 8];
          sb[wv * 64 + lane] = s * (K * 2);
          wl[wv * 64 + lane] = make_float4(__expf(lrelu(av.x + adv.x) - m0) * i0,
                                           __expf(lrelu(av.y + adv.y) - m1) * i1,
                                           __expf(lrelu(av.z + adv.z) - m2) * i2,
                                           __expf(lrelu(av.w + adv.w) - m3) * i3);
        }
        __builtin_amdgcn_wave_barrier();
        for (int g = 0; g < ne; ++g)
          edge_fma(fb + (size_t)sb[wv * 64 + g] + loff, wl[wv * 64 + g]);
        __builtin_amdgcn_wave_barrier();
      }
    }

#pragma unroll
    for (int j = 0; j < 4; ++j) {
      if (KC == 4) {
        uint2 ov;
        ov.x = pack2bf(acc[j][0], acc[j][1]);
        ov.y = pack2bf(acc[j][2], acc[j][3]);
        *(uint2*)&agg[(size_t)n * (4 * K) + j * K + lane * 4] = ov;
      } else {
        *(uint32_t*)&agg[(size_t)n * (4 * K) + j * K + lane * 2] = pack2bf(acc[j][0], acc[j][1]);
      }
    }
  }
}

// input-space GAT aggregation, H=1, K=128
__device__ void gather1_dev(char* smem, const bf16_t* f, const float* asad,
                            const int* rp, const int* cs, bf16_t* agg, int N) {
  int* sb = (int*)smem;                // [4][64]
  float* wl = (float*)(smem + 1024);   // [4][64]
  const int wv = threadIdx.x >> 6, lane = threadIdx.x & 63;
  const char* fb = (const char*)f;
  const size_t loff = (size_t)lane * 4;

  for (int grp = blockIdx.x; grp < N / 4; grp += gridDim.x) {
    const int n = grp * 4 + wv;
    const int r0 = rp[n], r1 = rp[n + 1];
    const int deg = r1 - r0;
    const float adv = asad[(size_t)n * 2 + 1];
    float a0 = 0.f, a1 = 0.f;

    auto fma2 = [&](uint32_t v, float w) { a0 += w * bflo(v); a1 += w * bfhi(v); };

    if (deg <= 64) {
      const bool valid = lane < deg;
      int s = 0;
      float e = -1e30f;
      if (valid) { s = cs[r0 + lane]; e = lrelu(asad[(size_t)s * 2] + adv); }
      float m = e;
#pragma unroll
      for (int d = 1; d < 64; d <<= 1) m = fmaxf(m, __shfl_xor(m, d));
      float x = valid ? __expf(e - m) : 0.f;
      float den = x;
#pragma unroll
      for (int d = 1; d < 64; d <<= 1) den += __shfl_xor(den, d);
      if (valid) { sb[wv * 64 + lane] = s * 256; wl[wv * 64 + lane] = x / (den + 1e-16f); }
      __builtin_amdgcn_wave_barrier();
      int g = 0;
      for (; g + 8 <= deg; g += 8) {
        uint32_t b[8];
        float w[8];
#pragma unroll
        for (int k = 0; k < 8; ++k) {
          b[k] = *(const uint32_t*)(fb + (size_t)sb[wv * 64 + g + k] + loff);
          w[k] = wl[wv * 64 + g + k];
        }
#pragma unroll
        for (int k = 0; k < 8; ++k) { a0 += w[k] * bflo(b[k]); a1 += w[k] * bfhi(b[k]); }
      }
      for (; g < deg; ++g)
        fma2(*(const uint32_t*)(fb + (size_t)sb[wv * 64 + g] + loff), wl[wv * 64 + g]);
    } else {
      float m = -1e30f;
      for (int i = r0 + lane; i < r1; i += 64) m = fmaxf(m, lrelu(asad[(size_t)cs[i] * 2] + adv));
#pragma unroll
      for (int d = 1; d < 64; d <<= 1) m = fmaxf(m, __shfl_xor(m, d));
      float den = 0.f;
      for (int i = r0 + lane; i < r1; i += 64) den += __expf(lrelu(asad[(size_t)cs[i] * 2] + adv) - m);
#pragma unroll
      for (int d = 1; d < 64; d <<= 1) den += __shfl_xor(den, d);
      const float dinv = 1.f / (den + 1e-16f);
      for (int base = r0; base < r1; base += 64) {
        const int ne = min(64, r1 - base);
        if (lane < ne) {
          const int s = cs[base + lane];
          sb[wv * 64 + lane] = s * 256;
          wl[wv * 64 + lane] = __expf(lrelu(asad[(size_t)s * 2] + adv) - m) * dinv;
        }
        __builtin_amdgcn_wave_barrier();
        for (int g = 0; g < ne; ++g)
          fma2(*(const uint32_t*)(fb + (size_t)sb[wv * 64 + g] + loff), wl[wv * 64 + g]);
        __builtin_amdgcn_wave_barrier();
      }
    }
    *(uint32_t*)&agg[(size_t)n * 128 + lane * 2] = pack2bf(a0, a1);
  }
}

// ---------------- the cooperative mega-kernel ----------------

__global__ void __launch_bounds__(256, 5) mega(MegaArgs a) {
  __shared__ __align__(16) char smem[24 * 1024];
  cg::grid_group grid = cg::this_grid();

  // P0: edge scatter + x cast + layer-1 alpha
  for (int b = blockIdx.x; b < a.EB + a.N / 4; b += gridDim.x)
    scatter_cast_dev(a, b);
  grid.sync();

  // P1: gather layer 1 (K=256)
  gather4_dev<256>(smem, a.xb, a.asadA, a.rp, a.col, a.aggb, a.N);
  grid.sync();

  // P2: gemm layer 1: f1 = relu(BN1(agg @ Ws1t + b1))
  gemm_dev(smem, a.aggb, a.Ws1t, a.b1, a.bn1g, a.bn1b, a.bn1m, a.bn1v, 3,
           a.f1b, nullptr, a.N, 128, 1024);
  grid.sync();

  // P3: alpha layer 2
  alpha_dev<128, 4>(a.f1b, a.P2, a.asadB, a.N);
  grid.sync();

  // P4: gather layer 2 (K=128)
  gather4_dev<128>(smem, a.f1b, a.asadB, a.rp, a.col, a.aggb, a.N);
  grid.sync();

  // P5: gemm layer 2
  gemm_dev(smem, a.aggb, a.Ws2t, a.b2, a.bn2g, a.bn2b, a.bn2m, a.bn2v, 3,
           a.f2b, nullptr, a.N, 128, 512);
  grid.sync();

  // P6: alpha layer 3
  alpha_dev<128, 1>(a.f2b, a.P3, a.asadC, a.N);
  grid.sync();

  // P7: gather layer 3 (H=1)
  gather1_dev(smem, a.f2b, a.asadC, a.rp, a.col, a.aggb, a.N);
  grid.sync();

  // P8: tail 1: m1 = relu(agg3 @ M3t + bm)   (GAT3 linear folded with MLP l1)
  gemm_dev(smem, a.aggb, a.M3t, a.bm, nullptr, nullptr, nullptr, nullptr, 1,
           a.f1b, nullptr, a.N, 128, 128);
  grid.sync();

  // P9: tail 2: m2 = relu(m1 @ l2t + l2b)
  gemm_dev(smem, a.f1b, a.l2t, a.l2b, nullptr, nullptr, nullptr, nullptr, 1,
           a.f2b, nullptr, a.N, 64, 128);
  grid.sync();

  // P10: tail 3: out = sigmoid(m2 @ l3t + l3b)
  gemm_dev(smem, a.f2b, a.l3t, a.l3b, nullptr, nullptr, nullptr, nullptr, 2,
           nullptr, a.out, a.N, 64, 64);
}

// ---------------- launch ----------------

extern "C" void kernel_launch(void* const* d_in, const int* in_sizes, int n_in,
                              void* d_out, int out_size, void* d_ws, size_t ws_size,
                              hipStream_t stream) {
  const float* x      = (const float*)d_in[0];
  const int*   ei     = (const int*)d_in[1];
  const float* W1     = (const float*)d_in[2];
  const float* a_src1 = (const float*)d_in[3];
  const float* a_dst1 = (const float*)d_in[4];
  const float* b1     = (const float*)d_in[5];
  const float* W2     = (const float*)d_in[6];
  const float* a_src2 = (const float*)d_in[7];
  const float* a_dst2 = (const float*)d_in[8];
  const float* b2     = (const float*)d_in[9];
  const float* W3     = (const float*)d_in[10];
  const float* a_src3 = (const float*)d_in[11];
  const float* a_dst3 = (const float*)d_in[12];
  const float* b3     = (const float*)d_in[13];
  const float* bn1g = (const float*)d_in[14];
  const float* bn1b = (const float*)d_in[15];
  const float* bn1m = (const float*)d_in[16];
  const float* bn1v = (const float*)d_in[17];
  const float* bn2g = (const float*)d_in[18];
  const float* bn2b = (const float*)d_in[19];
  const float* bn2m = (const float*)d_in[20];
  const float* bn2v = (const float*)d_in[21];
  const float* l1w = (const float*)d_in[22];
  const float* l1b = (const float*)d_in[23];
  const float* l2w = (const float*)d_in[24];
  const float* l2b = (const float*)d_in[25];
  const float* l3w = (const float*)d_in[26];
  const float* l3b = (const float*)d_in[27];
  float* out = (float*)d_out;

  const int N = NN;
  const int E = in_sizes[1] / 2;
  const int ET = E + N;
  const int EB = (ET + 255) / 256;

  char* p = (char*)d_ws;
  auto carve = [&](size_t bytes) {
    char* q = p;
    p += (bytes + 255) & ~(size_t)255;
    return q;
  };
  bf16_t* xb    = (bf16_t*)carve((size_t)N * 256 * 2);
  bf16_t* aggb  = (bf16_t*)carve((size_t)N * 1024 * 2);
  bf16_t* f1b   = (bf16_t*)carve((size_t)N * 128 * 2);
  bf16_t* f2b   = (bf16_t*)carve((size_t)N * 128 * 2);
  float* asadA  = (float*)carve((size_t)N * 8 * 4);
  float* asadB  = (float*)carve((size_t)N * 8 * 4);
  float* asadC  = (float*)carve((size_t)N * 2 * 4);
  int* cnt      = (int*)carve((size_t)N * 4);
  int* cursor   = (int*)carve((size_t)N * 4);
  int* row_ptr  = (int*)carve((size_t)(N + 1) * 4);
  int* col      = (int*)carve((size_t)ET * 4);
  bf16_t* Ws1t  = (bf16_t*)carve((size_t)128 * 1024 * 2);
  bf16_t* Ws2t  = (bf16_t*)carve((size_t)128 * 512 * 2);
  bf16_t* M3t   = (bf16_t*)carve((size_t)128 * 128 * 2);
  bf16_t* l2t   = (bf16_t*)carve((size_t)64 * 128 * 2);
  bf16_t* l3t   = (bf16_t*)carve((size_t)64 * 64 * 2);
  float* P1     = (float*)carve((size_t)8 * 256 * 4);
  float* P2     = (float*)carve((size_t)8 * 128 * 4);
  float* P3     = (float*)carve((size_t)2 * 128 * 4);
  float* bm     = (float*)carve((size_t)128 * 4);
  (void)ws_size; (void)n_in; (void)out_size;

  hipMemsetAsync(cnt, 0, (size_t)N * 4, stream);

  Prep1Args pa;
  pa.wp.d[0] = {W1,  Ws1t, 256, 128, 4, 0.25f, 0};
  pa.wp.d[1] = {W2,  Ws2t, 128, 128, 4, 0.25f, 128};
  pa.wp.d[2] = {l2w, l2t,  128, 64,  1, 1.0f,  192};
  pa.wp.d[3] = {l3w, l3t,  64,  64,  1, 1.0f,  200};
  pa.W1 = W1; pa.as1 = a_src1; pa.ad1 = a_dst1;
  pa.W2 = W2; pa.as2 = a_src2; pa.ad2 = a_dst2;
  pa.W3 = W3; pa.as3 = a_src3; pa.ad3 = a_dst3;
  pa.P1 = P1; pa.P2 = P2; pa.P3 = P3;
  pa.W3m = W3; pa.L1w = l1w; pa.b3v = b3; pa.l1b = l1b;
  pa.M3t = M3t; pa.bm = bm;
  pa.ei = ei; pa.E = E; pa.N = N; pa.EB = EB;
  pa.cnt = cnt;
  prep1<<<780 + EB, 256, 0, stream>>>(pa);

  scan_kernel<<<1, 1024, 0, stream>>>(cnt, row_ptr, cursor, N);

  // cooperative pipeline kernel
  int maxB = 0;
  hipOccupancyMaxActiveBlocksPerMultiprocessor(&maxB, mega, 256, 0);
  if (maxB < 1) maxB = 1;
  if (maxB > 6) maxB = 6;
  const int nblk = maxB * 256;  // 256 CUs on MI355X

  MegaArgs ma;
  ma.ei = ei; ma.E = E; ma.N = N; ma.EB = EB;
  ma.cursor = cursor; ma.col = col;
  ma.x = x; ma.P1 = P1; ma.xb = xb; ma.asadA = asadA;
  ma.aggb = aggb; ma.f1b = f1b; ma.f2b = f2b;
  ma.asadB = asadB; ma.asadC = asadC;
  ma.rp = row_ptr;
  ma.Ws1t = Ws1t; ma.Ws2t = Ws2t; ma.M3t = M3t; ma.l2t = l2t; ma.l3t = l3t;
  ma.P2 = P2; ma.P3 = P3;
  ma.b1 = b1; ma.bn1g = bn1g; ma.bn1b = bn1b; ma.bn1m = bn1m; ma.bn1v = bn1v;
  ma.b2 = b2; ma.bn2g = bn2g; ma.bn2b = bn2b; ma.bn2m = bn2m; ma.bn2v = bn2v;
  ma.bm = bm; ma.l2b = l2b; ma.l3b = l3b;
  ma.out = out;

  void* kargs[] = {&ma};
  hipLaunchCooperativeKernel((const void*)mega, dim3(nblk), dim3(256), kargs, 0, stream);
}

// Round 11
// 336.108 us; speedup vs baseline: 3.1061x; 3.1061x over previous
//
#include <hip/hip_runtime.h>
#include <cstdint>
#include <cstddef>

#define NN 20000

typedef __bf16 bf16_t;
typedef __bf16 bf16x8 __attribute__((ext_vector_type(8)));
typedef float f32x4 __attribute__((ext_vector_type(4)));

#define AS1 __attribute__((address_space(1)))
#define AS3 __attribute__((address_space(3)))

__device__ __forceinline__ float lrelu(float x) { return x >= 0.f ? x : 0.2f * x; }
__device__ __forceinline__ float bflo(uint32_t u) { return __uint_as_float(u << 16); }
__device__ __forceinline__ float bfhi(uint32_t u) { return __uint_as_float(u & 0xffff0000u); }

__device__ __forceinline__ uint32_t pack2bf(float a, float b) {
  bf16_t x = (bf16_t)a, y = (bf16_t)b;
  uint16_t ux = __builtin_bit_cast(uint16_t, x);
  uint16_t uy = __builtin_bit_cast(uint16_t, y);
  return (uint32_t)ux | ((uint32_t)uy << 16);
}

// ---------------- CSR scan ----------------

__global__ __launch_bounds__(1024) void scan_kernel(const int* __restrict__ cnt,
                                                    int* __restrict__ row_ptr,
                                                    int* __restrict__ cursor, int n) {
  __shared__ int wsum[16];
  const int t = threadIdx.x;
  const int lane = t & 63, w = t >> 6;
  int carry = 0;
  for (int base = 0; base < n; base += 1024) {
    int i = base + t;
    int v = (i < n) ? cnt[i] : 0;
    int x = v;
#pragma unroll
    for (int d = 1; d < 64; d <<= 1) {
      int y = __shfl_up(x, d);
      if (lane >= d) x += y;
    }
    if (lane == 63) wsum[w] = x;
    __syncthreads();
    if (t < 16) {
      int s = wsum[t];
#pragma unroll
      for (int d = 1; d < 16; d <<= 1) {
        int y = __shfl_up(s, d);
        if (t >= d) s += y;
      }
      wsum[t] = s;
    }
    __syncthreads();
    int blocksum = wsum[15];
    int wprefix = (w == 0) ? 0 : wsum[w - 1];
    int excl = carry + wprefix + (x - v);
    if (i < n) { row_ptr[i] = excl; cursor[i] = excl; }
    carry += blocksum;
    __syncthreads();
  }
  if (t == 0) row_ptr[n] = carry;
}

// ---------------- prep mega-kernel ----------------
// block ranges: [0,204) wprep | [204,716) alpha_proj | [716,780) merge_w3l1 | [780,780+EB) hist

struct WDesc { const float* W; bf16_t* Bt; int K; int Cw; int H; float scale; int b0; };
struct WPack { WDesc d[4]; };

struct Prep1Args {
  WPack wp;
  const float *W1, *as1, *ad1, *W2, *as2, *ad2, *W3, *as3, *ad3;
  float *P1, *P2, *P3;
  const float *W3m, *L1w, *b3v, *l1b;
  bf16_t* M3t; float* bm;
  const int* ei; int E, N, EB;
  int* cnt;
};

__global__ __launch_bounds__(256) void prep1(Prep1Args a) {
  __shared__ float tile[32][33];
  const int b = blockIdx.x;
  const int t = threadIdx.x;

  if (b < 204) {
    int i = 3;
#pragma unroll
    for (int k = 2; k >= 0; --k)
      if (b < a.wp.d[k + 1].b0) i = k;
    const WDesc de = a.wp.d[i];
    const int bi = b - de.b0;
    const int ktiles = de.K / 32;
    const int kt = bi % ktiles, rt = bi / ktiles;
    const int gc = rt * 32;
    const int h = gc / de.Cw, c0 = gc % de.Cw;
    const int tx = t & 31, ty = t >> 5;
#pragma unroll
    for (int r = 0; r < 32; r += 8)
      tile[ty + r][tx] = de.W[(size_t)(kt * 32 + ty + r) * (de.H * de.Cw) + h * de.Cw + c0 + tx];
    __syncthreads();
#pragma unroll
    for (int r = 0; r < 32; r += 8)
      de.Bt[(size_t)(c0 + ty + r) * (de.H * de.K) + h * de.K + kt * 32 + tx] =
          (bf16_t)(de.scale * tile[tx][ty + r]);
  } else if (b < 716) {
    const int kk = b - 204;
    const float *W, *asrc, *adst;
    float* P;
    int K, H, k;
    if (kk < 256)      { W = a.W1; asrc = a.as1; adst = a.ad1; P = a.P1; K = 256; H = 4; k = kk; }
    else if (kk < 384) { W = a.W2; asrc = a.as2; adst = a.ad2; P = a.P2; K = 128; H = 4; k = kk - 256; }
    else               { W = a.W3; asrc = a.as3; adst = a.ad3; P = a.P3; K = 128; H = 1; k = kk - 384; }
    for (int j = 0; j < 2 * H; ++j) {
      const int h = (j < H) ? j : j - H;
      const float* av = (j < H) ? asrc : adst;
      float pv = 0.f;
      if (t < 128) pv = W[(size_t)k * (H * 128) + h * 128 + t] * av[h * 128 + t];
#pragma unroll
      for (int d = 1; d < 64; d <<= 1) pv += __shfl_xor(pv, d);
      if (t == 0 || t == 64) tile[0][t >> 6] = pv;
      __syncthreads();
      if (t == 0) P[j * K + k] = tile[0][0] + tile[0][1];
      __syncthreads();
    }
  } else if (b < 780) {
    const int idx = (b - 716) * 256 + t;
    const int k = idx >> 7, c = idx & 127;
    float s = 0.f;
    for (int m = 0; m < 128; ++m) s += a.W3m[k * 128 + m] * a.L1w[m * 128 + c];
    a.M3t[c * 128 + k] = (bf16_t)s;
    if (k == 0) {
      float tt = a.l1b[c];
      for (int m = 0; m < 128; ++m) tt += a.b3v[m] * a.L1w[m * 128 + c];
      a.bm[c] = tt;
    }
  } else {
    const int i = (b - 780) * 256 + t;
    if (i < a.E + a.N) {
      int dst = (i < a.E) ? a.ei[a.E + i] : (i - a.E);
      atomicAdd(&a.cnt[dst], 1);
    }
  }
}

// ---------------- scatter + fused cast+layer1-alpha ----------------

__global__ __launch_bounds__(256) void scatter_cast(const int* __restrict__ ei, int E, int N,
                                                    int EB, int* __restrict__ cursor,
                                                    int* __restrict__ col,
                                                    const float* __restrict__ x,
                                                    const float* __restrict__ P1,
                                                    bf16_t* __restrict__ xb,
                                                    float* __restrict__ asadA) {
  const int b = blockIdx.x, t = threadIdx.x;
  if (b < EB) {
    const int i = b * 256 + t;
    if (i < E + N) {
      int src, dst;
      if (i < E) { src = ei[i]; dst = ei[E + i]; }
      else       { src = i - E; dst = src; }
      int slot = atomicAdd(&cursor[dst], 1);
      col[slot] = src;
    }
  } else {
    const int wv = t >> 6, lane = t & 63;
    const int n = (b - EB) * 4 + wv;
    const float4 v = *(const float4*)&x[(size_t)n * 256 + lane * 4];
    uint2 ov;
    ov.x = pack2bf(v.x, v.y);
    ov.y = pack2bf(v.z, v.w);
    *(uint2*)&xb[(size_t)n * 256 + lane * 4] = ov;
    float s[8];
#pragma unroll
    for (int j = 0; j < 8; ++j) {
      const float4 pj = *(const float4*)&P1[j * 256 + lane * 4];
      s[j] = v.x * pj.x + v.y * pj.y + v.z * pj.z + v.w * pj.w;
    }
#pragma unroll
    for (int j = 0; j < 8; ++j)
#pragma unroll
      for (int d = 1; d < 64; d <<= 1) s[j] += __shfl_xor(s[j], d);
    if (lane == 0) {
#pragma unroll
      for (int j = 0; j < 8; ++j) asadA[(size_t)n * 8 + j] = s[j];
    }
  }
}

// ---------------- bf16 MFMA GEMM: C = act(A @ Bt^T + bias) ----------------
// ACT: 1=relu, 3=BN(eval)+relu

template <int TN, int ACT, typename OUT_T>
__global__ __launch_bounds__(256) void gemm_mfma(const bf16_t* __restrict__ A,
                                                 const bf16_t* __restrict__ Bt,
                                                 const float* __restrict__ bias,
                                                 const float* __restrict__ bng,
                                                 const float* __restrict__ bnb,
                                                 const float* __restrict__ bnm,
                                                 const float* __restrict__ bnv,
                                                 OUT_T* __restrict__ C,
                                                 int M, int N, int K) {
  constexpr int TM = 128, BK = 64;
  constexpr int MT = (TN == 128) ? 4 : 2;
  constexpr int NRB = (TN * BK * 2) / 4096;
  __shared__ __align__(16) bf16_t As[TM * BK];
  __shared__ __align__(16) bf16_t Bs[TN * BK];

  const int t = threadIdx.x;
  const int wave = t >> 6, lane = t & 63;
  const int ln15 = lane & 15, quad = lane >> 4;
  const int bm = blockIdx.x * TM;
  const int bn = blockIdx.y * TN;
  const int wm = (TN == 128) ? (wave >> 1) * 64 : wave * 32;
  const int wn = (TN == 128) ? (wave & 1) * 64 : 0;
  const int rowLimA = M - 1 - bm;
  const size_t strideAB = (size_t)K * 2;

  f32x4 acc[MT][4];
#pragma unroll
  for (int mi = 0; mi < MT; ++mi)
#pragma unroll
    for (int ni = 0; ni < 4; ++ni) acc[mi][ni] = (f32x4){0.f, 0.f, 0.f, 0.f};

  const char* gA = (const char*)(A + (size_t)bm * K);
  const char* gB = (const char*)(Bt + (size_t)bn * K);

  for (int k0 = 0; k0 < K; k0 += BK) {
#pragma unroll
    for (int r = 0; r < 4; ++r) {
      int base = (wave * 4 + r) * 1024;
      int flat = base + lane * 16;
      int row = flat >> 7;
      int grow = row < rowLimA ? row : rowLimA;
      const char* gp = gA + (size_t)grow * strideAB + (size_t)(k0 * 2) + (flat & 127);
      __builtin_amdgcn_global_load_lds((const AS1 void*)gp,
                                       (AS3 void*)((char*)As + base), 16, 0, 0);
    }
#pragma unroll
    for (int r = 0; r < NRB; ++r) {
      int base = (wave * NRB + r) * 1024;
      int flat = base + lane * 16;
      int row = flat >> 7;
      const char* gp = gB + (size_t)row * strideAB + (size_t)(k0 * 2) + (flat & 127);
      __builtin_amdgcn_global_load_lds((const AS1 void*)gp,
                                       (AS3 void*)((char*)Bs + base), 16, 0, 0);
    }
    __syncthreads();
#pragma unroll
    for (int kk = 0; kk < BK; kk += 32) {
      bf16x8 af[MT], bfr[4];
#pragma unroll
      for (int mi = 0; mi < MT; ++mi)
        af[mi] = *(const bf16x8*)&As[(wm + mi * 16 + ln15) * BK + kk + quad * 8];
#pragma unroll
      for (int ni = 0; ni < 4; ++ni)
        bfr[ni] = *(const bf16x8*)&Bs[(wn + ni * 16 + ln15) * BK + kk + quad * 8];
#pragma unroll
      for (int mi = 0; mi < MT; ++mi)
#pragma unroll
        for (int ni = 0; ni < 4; ++ni)
          acc[mi][ni] = __builtin_amdgcn_mfma_f32_16x16x32_bf16(af[mi], bfr[ni], acc[mi][ni], 0, 0, 0);
    }
    __syncthreads();
  }

#pragma unroll
  for (int mi = 0; mi < MT; ++mi) {
    int r0 = bm + wm + mi * 16 + quad * 4;
#pragma unroll
    for (int ni = 0; ni < 4; ++ni) {
      int c = bn + wn + ni * 16 + ln15;
      float bv = bias ? bias[c] : 0.f;
      float sc = 1.f, sh = 0.f;
      if (ACT == 3) {
        sc = bng[c] * rsqrtf(bnv[c] + 1e-5f);
        sh = bnb[c] - bnm[c] * sc;
      }
#pragma unroll
      for (int reg = 0; reg < 4; ++reg) {
        int r = r0 + reg;
        if (r < M) {
          float v = acc[mi][ni][reg] + bv;
          if (ACT == 1) v = fmaxf(v, 0.f);
          else if (ACT == 3) v = fmaxf(v * sc + sh, 0.f);
          C[(size_t)r * N + c] = (OUT_T)v;
        }
      }
    }
  }
}

// ---------------- alpha logits for layers 2/3: asad[n, j] = f[n,:] . P[j,:] ----------

template <int K, int H>
__global__ __launch_bounds__(256) void alpha_gemm(const bf16_t* __restrict__ f,
                                                  const float* __restrict__ P,
                                                  float* __restrict__ asad) {
  constexpr int J = 2 * H;
  constexpr int KC = K / 64;
  const int wv = threadIdx.x >> 6, lane = threadIdx.x & 63;
  const int n = blockIdx.x * 4 + wv;
  float v[KC];
  if (KC == 4) {
    uint2 pv = *(const uint2*)&f[(size_t)n * K + lane * 4];
    v[0] = bflo(pv.x); v[1] = bfhi(pv.x); v[2] = bflo(pv.y); v[3] = bfhi(pv.y);
  } else {
    uint32_t pv = *(const uint32_t*)&f[(size_t)n * K + lane * 2];
    v[0] = bflo(pv); v[1] = bfhi(pv);
  }
  float s[J];
#pragma unroll
  for (int j = 0; j < J; ++j) {
    float acc = 0.f;
#pragma unroll
    for (int q = 0; q < KC; ++q) acc += v[q] * P[j * K + lane * KC + q];
    s[j] = acc;
  }
#pragma unroll
  for (int j = 0; j < J; ++j)
#pragma unroll
    for (int d = 1; d < 64; d <<= 1) s[j] += __shfl_xor(s[j], d);
  if (lane == 0) {
#pragma unroll
    for (int j = 0; j < J; ++j) asad[(size_t)n * J + j] = s[j];
  }
}

// ---------------- input-space GAT aggregation, H=4: wave/node, 2 nodes/block ---------

template <int K>
__global__ __launch_bounds__(128) void gat_agg_in4(const bf16_t* __restrict__ f,
                                                   const float* __restrict__ asad,
                                                   const int* __restrict__ rp,
                                                   const int* __restrict__ cs,
                                                   bf16_t* __restrict__ agg) {
  constexpr int KC = K / 64;
  const int wv = threadIdx.x >> 6, lane = threadIdx.x & 63;
  const int n = blockIdx.x * 2 + wv;
  __shared__ int sb[2][64];
  __shared__ float4 wl[2][64];

  const int r0 = rp[n], r1 = rp[n + 1];
  const int deg = r1 - r0;
  const float4 adv = *(const float4*)&asad[(size_t)n * 8 + 4];
  const char* fb = (const char*)f;
  const size_t loff = (size_t)lane * (KC * 2);

  float acc[4][KC];
#pragma unroll
  for (int j = 0; j < 4; ++j)
#pragma unroll
    for (int q = 0; q < KC; ++q) acc[j][q] = 0.f;

  auto edge_fma = [&](const char* gp, float4 w4) {
    if (KC == 4) {
      uint2 b = *(const uint2*)gp;
      float v0 = bflo(b.x), v1 = bfhi(b.x), v2 = bflo(b.y), v3 = bfhi(b.y);
      acc[0][0] += w4.x * v0; acc[0][1] += w4.x * v1; acc[0][2] += w4.x * v2; acc[0][3] += w4.x * v3;
      acc[1][0] += w4.y * v0; acc[1][1] += w4.y * v1; acc[1][2] += w4.y * v2; acc[1][3] += w4.y * v3;
      acc[2][0] += w4.z * v0; acc[2][1] += w4.z * v1; acc[2][2] += w4.z * v2; acc[2][3] += w4.z * v3;
      acc[3][0] += w4.w * v0; acc[3][1] += w4.w * v1; acc[3][2] += w4.w * v2; acc[3][3] += w4.w * v3;
    } else {
      uint32_t b = *(const uint32_t*)gp;
      float v0 = bflo(b), v1 = bfhi(b);
      acc[0][0] += w4.x * v0; acc[0][1] += w4.x * v1;
      acc[1][0] += w4.y * v0; acc[1][1] += w4.y * v1;
      acc[2][0] += w4.z * v0; acc[2][1] += w4.z * v1;
      acc[3][0] += w4.w * v0; acc[3][1] += w4.w * v1;
    }
  };

  if (deg <= 64) {
    const bool valid = lane < deg;
    int s = 0;
    float e0 = -1e30f, e1 = -1e30f, e2 = -1e30f, e3 = -1e30f;
    if (valid) {
      s = cs[r0 + lane];
      const float4 av = *(const float4*)&asad[(size_t)s * 8];
      e0 = lrelu(av.x + adv.x); e1 = lrelu(av.y + adv.y);
      e2 = lrelu(av.z + adv.z); e3 = lrelu(av.w + adv.w);
    }
    float m0 = e0, m1 = e1, m2 = e2, m3 = e3;
#pragma unroll
    for (int d = 1; d < 64; d <<= 1) {
      m0 = fmaxf(m0, __shfl_xor(m0, d)); m1 = fmaxf(m1, __shfl_xor(m1, d));
      m2 = fmaxf(m2, __shfl_xor(m2, d)); m3 = fmaxf(m3, __shfl_xor(m3, d));
    }
    float x0 = valid ? __expf(e0 - m0) : 0.f;
    float x1 = valid ? __expf(e1 - m1) : 0.f;
    float x2 = valid ? __expf(e2 - m2) : 0.f;
    float x3 = valid ? __expf(e3 - m3) : 0.f;
    float d0 = x0, d1 = x1, d2 = x2, d3 = x3;
#pragma unroll
    for (int d = 1; d < 64; d <<= 1) {
      d0 += __shfl_xor(d0, d); d1 += __shfl_xor(d1, d);
      d2 += __shfl_xor(d2, d); d3 += __shfl_xor(d3, d);
    }
    if (valid) {
      sb[wv][lane] = s * (K * 2);
      wl[wv][lane] = make_float4(x0 / (d0 + 1e-16f), x1 / (d1 + 1e-16f),
                                 x2 / (d2 + 1e-16f), x3 / (d3 + 1e-16f));
    }
    __builtin_amdgcn_wave_barrier();

    int g = 0;
    for (; g + 8 <= deg; g += 8) {
      const char* p[8];
      float4 w[8];
#pragma unroll
      for (int k = 0; k < 8; ++k) { p[k] = fb + (size_t)sb[wv][g + k] + loff; w[k] = wl[wv][g + k]; }
      if (KC == 4) {
        uint2 b[8];
#pragma unroll
        for (int k = 0; k < 8; ++k) b[k] = *(const uint2*)p[k];
#pragma unroll
        for (int k = 0; k < 8; ++k) {
          float v0 = bflo(b[k].x), v1 = bfhi(b[k].x), v2 = bflo(b[k].y), v3 = bfhi(b[k].y);
          acc[0][0] += w[k].x * v0; acc[0][1] += w[k].x * v1; acc[0][2] += w[k].x * v2; acc[0][3] += w[k].x * v3;
          acc[1][0] += w[k].y * v0; acc[1][1] += w[k].y * v1; acc[1][2] += w[k].y * v2; acc[1][3] += w[k].y * v3;
          acc[2][0] += w[k].z * v0; acc[2][1] += w[k].z * v1; acc[2][2] += w[k].z * v2; acc[2][3] += w[k].z * v3;
          acc[3][0] += w[k].w * v0; acc[3][1] += w[k].w * v1; acc[3][2] += w[k].w * v2; acc[3][3] += w[k].w * v3;
        }
      } else {
        uint32_t b[8];
#pragma unroll
        for (int k = 0; k < 8; ++k) b[k] = *(const uint32_t*)p[k];
#pragma unroll
        for (int k = 0; k < 8; ++k) {
          float v0 = bflo(b[k]), v1 = bfhi(b[k]);
          acc[0][0] += w[k].x * v0; acc[0][1] += w[k].x * v1;
          acc[1][0] += w[k].y * v0; acc[1][1] += w[k].y * v1;
          acc[2][0] += w[k].z * v0; acc[2][1] += w[k].z * v1;
          acc[3][0] += w[k].w * v0; acc[3][1] += w[k].w * v1;
        }
      }
    }
    for (; g < deg; ++g)
      edge_fma(fb + (size_t)sb[wv][g] + loff, wl[wv][g]);
  } else {
    float m0 = -1e30f, m1 = -1e30f, m2 = -1e30f, m3 = -1e30f;
    for (int i = r0 + lane; i < r1; i += 64) {
      const float4 av = *(const float4*)&asad[(size_t)cs[i] * 8];
      m0 = fmaxf(m0, lrelu(av.x + adv.x)); m1 = fmaxf(m1, lrelu(av.y + adv.y));
      m2 = fmaxf(m2, lrelu(av.z + adv.z)); m3 = fmaxf(m3, lrelu(av.w + adv.w));
    }
#pragma unroll
    for (int d = 1; d < 64; d <<= 1) {
      m0 = fmaxf(m0, __shfl_xor(m0, d)); m1 = fmaxf(m1, __shfl_xor(m1, d));
      m2 = fmaxf(m2, __shfl_xor(m2, d)); m3 = fmaxf(m3, __shfl_xor(m3, d));
    }
    float d0 = 0.f, d1 = 0.f, d2 = 0.f, d3 = 0.f;
    for (int i = r0 + lane; i < r1; i += 64) {
      const float4 av = *(const float4*)&asad[(size_t)cs[i] * 8];
      d0 += __expf(lrelu(av.x + adv.x) - m0); d1 += __expf(lrelu(av.y + adv.y) - m1);
      d2 += __expf(lrelu(av.z + adv.z) - m2); d3 += __expf(lrelu(av.w + adv.w) - m3);
    }
#pragma unroll
    for (int d = 1; d < 64; d <<= 1) {
      d0 += __shfl_xor(d0, d); d1 += __shfl_xor(d1, d);
      d2 += __shfl_xor(d2, d); d3 += __shfl_xor(d3, d);
    }
    const float i0 = 1.f / (d0 + 1e-16f), i1 = 1.f / (d1 + 1e-16f);
    const float i2 = 1.f / (d2 + 1e-16f), i3 = 1.f / (d3 + 1e-16f);
    for (int base = r0; base < r1; base += 64) {
      const int ne = min(64, r1 - base);
      if (lane < ne) {
        const int s = cs[base + lane];
        const float4 av = *(const float4*)&asad[(size_t)s * 8];
        sb[wv][lane] = s * (K * 2);
        wl[wv][lane] = make_float4(__expf(lrelu(av.x + adv.x) - m0) * i0,
                                   __expf(lrelu(av.y + adv.y) - m1) * i1,
                                   __expf(lrelu(av.z + adv.z) - m2) * i2,
                                   __expf(lrelu(av.w + adv.w) - m3) * i3);
      }
      __builtin_amdgcn_wave_barrier();
      for (int g = 0; g < ne; ++g)
        edge_fma(fb + (size_t)sb[wv][g] + loff, wl[wv][g]);
      __builtin_amdgcn_wave_barrier();
    }
  }

#pragma unroll
  for (int j = 0; j < 4; ++j) {
    if (KC == 4) {
      uint2 ov;
      ov.x = pack2bf(acc[j][0], acc[j][1]);
      ov.y = pack2bf(acc[j][2], acc[j][3]);
      *(uint2*)&agg[(size_t)n * (4 * K) + j * K + lane * 4] = ov;
    } else {
      *(uint32_t*)&agg[(size_t)n * (4 * K) + j * K + lane * 2] = pack2bf(acc[j][0], acc[j][1]);
    }
  }
}

// ---------------- input-space GAT aggregation, H=1 (K=128): 2 nodes/block ------------

__global__ __launch_bounds__(128) void gat_agg_in1(const bf16_t* __restrict__ f,
                                                   const float* __restrict__ asad,
                                                   const int* __restrict__ rp,
                                                   const int* __restrict__ cs,
                                                   bf16_t* __restrict__ agg) {
  const int wv = threadIdx.x >> 6, lane = threadIdx.x & 63;
  const int n = blockIdx.x * 2 + wv;
  __shared__ int sb[2][64];
  __shared__ float wl[2][64];

  const int r0 = rp[n], r1 = rp[n + 1];
  const int deg = r1 - r0;
  const float adv = asad[(size_t)n * 2 + 1];
  const char* fb = (const char*)f;
  const size_t loff = (size_t)lane * 4;
  float a0 = 0.f, a1 = 0.f;

  auto fma2 = [&](uint32_t v, float w) { a0 += w * bflo(v); a1 += w * bfhi(v); };

  if (deg <= 64) {
    const bool valid = lane < deg;
    int s = 0;
    float e = -1e30f;
    if (valid) { s = cs[r0 + lane]; e = lrelu(asad[(size_t)s * 2] + adv); }
    float m = e;
#pragma unroll
    for (int d = 1; d < 64; d <<= 1) m = fmaxf(m, __shfl_xor(m, d));
    float x = valid ? __expf(e - m) : 0.f;
    float den = x;
#pragma unroll
    for (int d = 1; d < 64; d <<= 1) den += __shfl_xor(den, d);
    if (valid) { sb[wv][lane] = s * 256; wl[wv][lane] = x / (den + 1e-16f); }
    __builtin_amdgcn_wave_barrier();
    int g = 0;
    for (; g + 8 <= deg; g += 8) {
      uint32_t b[8];
      float w[8];
#pragma unroll
      for (int k = 0; k < 8; ++k) {
        b[k] = *(const uint32_t*)(fb + (size_t)sb[wv][g + k] + loff);
        w[k] = wl[wv][g + k];
      }
#pragma unroll
      for (int k = 0; k < 8; ++k) { a0 += w[k] * bflo(b[k]); a1 += w[k] * bfhi(b[k]); }
    }
    for (; g < deg; ++g)
      fma2(*(const uint32_t*)(fb + (size_t)sb[wv][g] + loff), wl[wv][g]);
  } else {
    float m = -1e30f;
    for (int i = r0 + lane; i < r1; i += 64) m = fmaxf(m, lrelu(asad[(size_t)cs[i] * 2] + adv));
#pragma unroll
    for (int d = 1; d < 64; d <<= 1) m = fmaxf(m, __shfl_xor(m, d));
    float den = 0.f;
    for (int i = r0 + lane; i < r1; i += 64) den += __expf(lrelu(asad[(size_t)cs[i] * 2] + adv) - m);
#pragma unroll
    for (int d = 1; d < 64; d <<= 1) den += __shfl_xor(den, d);
    const float dinv = 1.f / (den + 1e-16f);
    for (int base = r0; base < r1; base += 64) {
      const int ne = min(64, r1 - base);
      if (lane < ne) {
        const int s = cs[base + lane];
        sb[wv][lane] = s * 256;
        wl[wv][lane] = __expf(lrelu(asad[(size_t)s * 2] + adv) - m) * dinv;
      }
      __builtin_amdgcn_wave_barrier();
      for (int g = 0; g < ne; ++g)
        fma2(*(const uint32_t*)(fb + (size_t)sb[wv][g] + loff), wl[wv][g]);
      __builtin_amdgcn_wave_barrier();
    }
  }
  *(uint32_t*)&agg[(size_t)n * 128 + lane * 2] = pack2bf(a0, a1);
}

// ---------------- fused classifier tail ----------------

__global__ __launch_bounds__(256) void mlp_tail(const bf16_t* __restrict__ A,
                                                const bf16_t* __restrict__ M3t,
                                                const float* __restrict__ bm,
                                                const bf16_t* __restrict__ l2t,
                                                const float* __restrict__ l2b,
                                                const bf16_t* __restrict__ l3t,
                                                const float* __restrict__ l3b,
                                                float* __restrict__ out, int M) {
  __shared__ __align__(16) bf16_t As[128 * 128];
  __shared__ __align__(16) bf16_t Ws[128 * 128];
  const int t = threadIdx.x, wave = t >> 6, lane = t & 63;
  const int ln15 = lane & 15, quad = lane >> 4;
  const int bmr = blockIdx.x * 128;
  const int rowLim = M - 1 - bmr;

#pragma unroll
  for (int r = 0; r < 8; ++r) {
    int base = (wave * 8 + r) * 1024;
    int flat = base + lane * 16;
    int row = flat >> 8;
    int grow = row < rowLim ? row : rowLim;
    const char* gp = (const char*)A + (size_t)grow * 256 + (flat & 255);
    __builtin_amdgcn_global_load_lds((const AS1 void*)gp,
                                     (AS3 void*)((char*)As + base), 16, 0, 0);
  }
#pragma unroll
  for (int r = 0; r < 8; ++r) {
    int base = (wave * 8 + r) * 1024;
    __builtin_amdgcn_global_load_lds((const AS1 void*)((const char*)M3t + base + lane * 16),
                                     (AS3 void*)((char*)Ws + base), 16, 0, 0);
  }
  __syncthreads();

  const int wm = wave * 32;
  f32x4 a1[2][8];
#pragma unroll
  for (int mi = 0; mi < 2; ++mi)
#pragma unroll
    for (int ni = 0; ni < 8; ++ni) a1[mi][ni] = (f32x4){0.f, 0.f, 0.f, 0.f};
#pragma unroll
  for (int kk = 0; kk < 128; kk += 32) {
    bf16x8 af[2];
#pragma unroll
    for (int mi = 0; mi < 2; ++mi)
      af[mi] = *(const bf16x8*)&As[(wm + mi * 16 + ln15) * 128 + kk + quad * 8];
#pragma unroll
    for (int ni = 0; ni < 8; ++ni) {
      bf16x8 bf = *(const bf16x8*)&Ws[(ni * 16 + ln15) * 128 + kk + quad * 8];
#pragma unroll
      for (int mi = 0; mi < 2; ++mi)
        a1[mi][ni] = __builtin_amdgcn_mfma_f32_16x16x32_bf16(af[mi], bf, a1[mi][ni], 0, 0, 0);
    }
  }
  __syncthreads();

#pragma unroll
  for (int r = 0; r < 4; ++r) {
    int base = (wave * 4 + r) * 1024;
    __builtin_amdgcn_global_load_lds((const AS1 void*)((const char*)l2t + base + lane * 16),
                                     (AS3 void*)((char*)Ws + base), 16, 0, 0);
  }
#pragma unroll
  for (int r = 0; r < 2; ++r) {
    int base = (wave * 2 + r) * 1024;
    __builtin_amdgcn_global_load_lds((const AS1 void*)((const char*)l3t + base + lane * 16),
                                     (AS3 void*)((char*)Ws + 8192 * 2 + base), 16, 0, 0);
  }
#pragma unroll
  for (int mi = 0; mi < 2; ++mi) {
    int r0 = wm + mi * 16 + quad * 4;
#pragma unroll
    for (int ni = 0; ni < 8; ++ni) {
      int c = ni * 16 + ln15;
      float bv = bm[c];
#pragma unroll
      for (int reg = 0; reg < 4; ++reg)
        As[(r0 + reg) * 128 + c] = (bf16_t)fmaxf(a1[mi][ni][reg] + bv, 0.f);
    }
  }
  __syncthreads();

  f32x4 a2[2][4];
#pragma unroll
  for (int mi = 0; mi < 2; ++mi)
#pragma unroll
    for (int ni = 0; ni < 4; ++ni) a2[mi][ni] = (f32x4){0.f, 0.f, 0.f, 0.f};
#pragma unroll
  for (int kk = 0; kk < 128; kk += 32) {
    bf16x8 af[2];
#pragma unroll
    for (int mi = 0; mi < 2; ++mi)
      af[mi] = *(const bf16x8*)&As[(wm + mi * 16 + ln15) * 128 + kk + quad * 8];
#pragma unroll
    for (int ni = 0; ni < 4; ++ni) {
      bf16x8 bf = *(const bf16x8*)&Ws[(ni * 16 + ln15) * 128 + kk + quad * 8];
#pragma unroll
      for (int mi = 0; mi < 2; ++mi)
        a2[mi][ni] = __builtin_amdgcn_mfma_f32_16x16x32_bf16(af[mi], bf, a2[mi][ni], 0, 0, 0);
    }
  }
  __syncthreads();

#pragma unroll
  for (int mi = 0; mi < 2; ++mi) {
    int r0 = wm + mi * 16 + quad * 4;
#pragma unroll
    for (int ni = 0; ni < 4; ++ni) {
      int c = ni * 16 + ln15;
      float bv = l2b[c];
#pragma unroll
      for (int reg = 0; reg < 4; ++reg)
        As[(r0 + reg) * 64 + c] = (bf16_t)fmaxf(a2[mi][ni][reg] + bv, 0.f);
    }
  }
  __syncthreads();

  f32x4 a3[2][4];
#pragma unroll
  for (int mi = 0; mi < 2; ++mi)
#pragma unroll
    for (int ni = 0; ni < 4; ++ni) a3[mi][ni] = (f32x4){0.f, 0.f, 0.f, 0.f};
#pragma unroll
  for (int kk = 0; kk < 64; kk += 32) {
    bf16x8 af[2];
#pragma unroll
    for (int mi = 0; mi < 2; ++mi)
      af[mi] = *(const bf16x8*)&As[(wm + mi * 16 + ln15) * 64 + kk + quad * 8];
#pragma unroll
    for (int ni = 0; ni < 4; ++ni) {
      bf16x8 bf = *(const bf16x8*)&Ws[8192 + (ni * 16 + ln15) * 64 + kk + quad * 8];
#pragma unroll
      for (int mi = 0; mi < 2; ++mi)
        a3[mi][ni] = __builtin_amdgcn_mfma_f32_16x16x32_bf16(af[mi], bf, a3[mi][ni], 0, 0, 0);
    }
  }
#pragma unroll
  for (int mi = 0; mi < 2; ++mi) {
    int r0 = wm + mi * 16 + quad * 4;
#pragma unroll
    for (int ni = 0; ni < 4; ++ni) {
      int c = ni * 16 + ln15;
      float bv = l3b[c];
#pragma unroll
      for (int reg = 0; reg < 4; ++reg) {
        int r = bmr + r0 + reg;
        if (r < M) {
          float v = a3[mi][ni][reg] + bv;
          out[(size_t)r * 64 + c] = 1.f / (1.f + __expf(-v));
        }
      }
    }
  }
}

// ---------------- launch ----------------

extern "C" void kernel_launch(void* const* d_in, const int* in_sizes, int n_in,
                              void* d_out, int out_size, void* d_ws, size_t ws_size,
                              hipStream_t stream) {
  const float* x      = (const float*)d_in[0];
  const int*   ei     = (const int*)d_in[1];
  const float* W1     = (const float*)d_in[2];
  const float* a_src1 = (const float*)d_in[3];
  const float* a_dst1 = (const float*)d_in[4];
  const float* b1     = (const float*)d_in[5];
  const float* W2     = (const float*)d_in[6];
  const float* a_src2 = (const float*)d_in[7];
  const float* a_dst2 = (const float*)d_in[8];
  const float* b2     = (const float*)d_in[9];
  const float* W3     = (const float*)d_in[10];
  const float* a_src3 = (const float*)d_in[11];
  const float* a_dst3 = (const float*)d_in[12];
  const float* b3     = (const float*)d_in[13];
  const float* bn1g = (const float*)d_in[14];
  const float* bn1b = (const float*)d_in[15];
  const float* bn1m = (const float*)d_in[16];
  const float* bn1v = (const float*)d_in[17];
  const float* bn2g = (const float*)d_in[18];
  const float* bn2b = (const float*)d_in[19];
  const float* bn2m = (const float*)d_in[20];
  const float* bn2v = (const float*)d_in[21];
  const float* l1w = (const float*)d_in[22];
  const float* l1b = (const float*)d_in[23];
  const float* l2w = (const float*)d_in[24];
  const float* l2b = (const float*)d_in[25];
  const float* l3w = (const float*)d_in[26];
  const float* l3b = (const float*)d_in[27];
  float* out = (float*)d_out;

  const int N = NN;
  const int E = in_sizes[1] / 2;
  const int ET = E + N;
  const int EB = (ET + 255) / 256;

  char* p = (char*)d_ws;
  auto carve = [&](size_t bytes) {
    char* q = p;
    p += (bytes + 255) & ~(size_t)255;
    return q;
  };
  bf16_t* xb    = (bf16_t*)carve((size_t)N * 256 * 2);
  bf16_t* aggb  = (bf16_t*)carve((size_t)N * 1024 * 2);
  bf16_t* f1b   = (bf16_t*)carve((size_t)N * 128 * 2);
  bf16_t* f2b   = (bf16_t*)carve((size_t)N * 128 * 2);
  float* asadA  = (float*)carve((size_t)N * 8 * 4);
  float* asadB  = (float*)carve((size_t)N * 8 * 4);
  float* asadC  = (float*)carve((size_t)N * 2 * 4);
  int* cnt      = (int*)carve((size_t)N * 4);
  int* cursor   = (int*)carve((size_t)N * 4);
  int* row_ptr  = (int*)carve((size_t)(N + 1) * 4);
  int* col      = (int*)carve((size_t)ET * 4);
  bf16_t* Ws1t  = (bf16_t*)carve((size_t)128 * 1024 * 2);
  bf16_t* Ws2t  = (bf16_t*)carve((size_t)128 * 512 * 2);
  bf16_t* M3t   = (bf16_t*)carve((size_t)128 * 128 * 2);
  bf16_t* l2t   = (bf16_t*)carve((size_t)64 * 128 * 2);
  bf16_t* l3t   = (bf16_t*)carve((size_t)64 * 64 * 2);
  float* P1     = (float*)carve((size_t)8 * 256 * 4);
  float* P2     = (float*)carve((size_t)8 * 128 * 4);
  float* P3     = (float*)carve((size_t)2 * 128 * 4);
  float* bm     = (float*)carve((size_t)128 * 4);
  (void)ws_size; (void)n_in; (void)out_size;

  hipMemsetAsync(cnt, 0, (size_t)N * 4, stream);

  Prep1Args pa;
  pa.wp.d[0] = {W1,  Ws1t, 256, 128, 4, 0.25f, 0};
  pa.wp.d[1] = {W2,  Ws2t, 128, 128, 4, 0.25f, 128};
  pa.wp.d[2] = {l2w, l2t,  128, 64,  1, 1.0f,  192};
  pa.wp.d[3] = {l3w, l3t,  64,  64,  1, 1.0f,  200};
  pa.W1 = W1; pa.as1 = a_src1; pa.ad1 = a_dst1;
  pa.W2 = W2; pa.as2 = a_src2; pa.ad2 = a_dst2;
  pa.W3 = W3; pa.as3 = a_src3; pa.ad3 = a_dst3;
  pa.P1 = P1; pa.P2 = P2; pa.P3 = P3;
  pa.W3m = W3; pa.L1w = l1w; pa.b3v = b3; pa.l1b = l1b;
  pa.M3t = M3t; pa.bm = bm;
  pa.ei = ei; pa.E = E; pa.N = N; pa.EB = EB;
  pa.cnt = cnt;
  prep1<<<780 + EB, 256, 0, stream>>>(pa);

  scan_kernel<<<1, 1024, 0, stream>>>(cnt, row_ptr, cursor, N);
  scatter_cast<<<EB + N / 4, 256, 0, stream>>>(ei, E, N, EB, cursor, col, x, P1, xb, asadA);

  const int gm = (N + 127) / 128;  // 157
  const int ab = N / 4;            // 5000
  const int gb = N / 2;            // 10000 gather blocks (2 nodes each)

  // --- GAT layer 1 ---
  gat_agg_in4<256><<<gb, 128, 0, stream>>>(xb, asadA, row_ptr, col, aggb);
  gemm_mfma<64, 3, bf16_t><<<dim3(gm, 2), 256, 0, stream>>>(
      aggb, Ws1t, b1, bn1g, bn1b, bn1m, bn1v, f1b, N, 128, 1024);

  // --- GAT layer 2 ---
  alpha_gemm<128, 4><<<ab, 256, 0, stream>>>(f1b, P2, asadB);
  gat_agg_in4<128><<<gb, 128, 0, stream>>>(f1b, asadB, row_ptr, col, aggb);
  gemm_mfma<64, 3, bf16_t><<<dim3(gm, 2), 256, 0, stream>>>(
      aggb, Ws2t, b2, bn2g, bn2b, bn2m, bn2v, f2b, N, 128, 512);

  // --- GAT layer 3 (H=1) + fused classifier tail ---
  alpha_gemm<128, 1><<<ab, 256, 0, stream>>>(f2b, P3, asadC);
  gat_agg_in1<<<gb, 128, 0, stream>>>(f2b, asadC, row_ptr, col, aggb);
  mlp_tail<<<gm, 256, 0, stream>>>(aggb, M3t, bm, l2t, l2b, l3t, l3b, out, N);
}